// Round 7
// baseline (986.278 us; speedup 1.0000x reference)
//
#include <hip/hip_runtime.h>
#include <hip/hip_bf16.h>
#include <cstdint>
#include <cstddef>

#define N_NODES 262143
#define LEAF0   131071
#define N_LEAF  131072
#define HSZ     256
#define XSZ     300
#define KX      320        // XSZ padded to multiple of 32
#define KU      512
#define GATES   1024       // 4*H
#define WCOLS   512        // 2*H
#define BM      128
#define BK      32

typedef short bf16x8 __attribute__((ext_vector_type(8)));
typedef float f32x4 __attribute__((ext_vector_type(4)));
typedef _Float16 f16;

__device__ __forceinline__ unsigned short f2bf(float f) {
  union { float f; unsigned u; } v; v.f = f;
  unsigned r = v.u + 0x7FFFu + ((v.u >> 16) & 1u);   // RNE
  return (unsigned short)(r >> 16);
}
__device__ __forceinline__ unsigned cvt_pk(float lo, float hi) {
  unsigned r;
  asm("v_cvt_pk_bf16_f32 %0, %1, %2" : "=v"(r) : "v"(lo), "v"(hi));
  return r;
}
__device__ __forceinline__ bf16x8 pack8(f32x4 a0, f32x4 a1) {
  union { unsigned u[4]; bf16x8 v; } r;
  r.u[0] = cvt_pk(a0[0], a0[1]);
  r.u[1] = cvt_pk(a0[2], a0[3]);
  r.u[2] = cvt_pk(a1[0], a1[1]);
  r.u[3] = cvt_pk(a1[2], a1[3]);
  return r.v;
}
__device__ __forceinline__ float frcp(float x) { return __builtin_amdgcn_rcpf(x); }
__device__ __forceinline__ float fsig(float x) { return frcp(1.f + __expf(-x)); }
__device__ __forceinline__ float ftanh_(float x) { return 1.f - 2.f * frcp(1.f + __expf(2.f * x)); }

// ---------------------------------------------------------------------------
// Prep: cast + column-permute + transpose W and U into ws (bf16).
// U perm col p = 64*b + 16*g + j  <-  orig col 256*g + 16*b + j
// W perm col p = 32*b + 16*s + j  <-  orig col 256*s + 16*b + j
// ---------------------------------------------------------------------------
__global__ void k_prep(const float* __restrict__ W, const float* __restrict__ U,
                       unsigned short* __restrict__ Wt, unsigned short* __restrict__ Ut) {
  int tid = blockIdx.x * blockDim.x + threadIdx.x;
  const int totalU = GATES * KU;
  if (tid < totalU) {
    int p = tid >> 9;
    int k = tid & 511;
    int g = (p >> 4) & 3, b = p >> 6, j = p & 15;
    int oc = g * 256 + b * 16 + j;
    Ut[tid] = f2bf(U[(size_t)k * GATES + oc]);
  } else {
    int t2 = tid - totalU;
    if (t2 < WCOLS * KX) {
      int p = t2 / KX;
      int k = t2 - p * KX;
      int s = (p >> 4) & 1, b = p >> 5, j = p & 15;
      int oc = s * 256 + b * 16 + j;
      Wt[t2] = (k < XSZ) ? f2bf(W[(size_t)k * WCOLS + oc]) : (unsigned short)0;
    }
  }
}

// ---------------------------------------------------------------------------
// Leaf init, barrier-free reg-GEMM. Block = 4 waves = 64 rows x 256 cols;
// wave w: cols nb + w*64. A frags loaded f32 -> cvt_pk -> bf16 in reg.
// grid = (N_LEAF/64) x 2.
// ---------------------------------------------------------------------------
__global__ __launch_bounds__(256) void k_init(
    const float* __restrict__ x, const unsigned short* __restrict__ Wt,
    const float* __restrict__ bW, float* __restrict__ hout,
    unsigned short* __restrict__ hb, f16* __restrict__ cb)
{
  const int t = threadIdx.x;
  const int lane = t & 63, w = t >> 6;
  const int lr = lane & 15, ls = lane >> 4;
  const int rb = (blockIdx.x >> 1) * 64;          // leaf-row block
  const int nb = (blockIdx.x & 1) * 256;          // perm-col block (of 512)

  f32x4 acc[4][4];
  #pragma unroll
  for (int i = 0; i < 4; ++i)
    #pragma unroll
    for (int j = 0; j < 4; ++j)
      #pragma unroll
      for (int e = 0; e < 4; ++e) acc[i][j][e] = 0.f;

  const size_t xend = (size_t)N_NODES * XSZ - 4;   // clamp for 16B loads
  const float* A0 = x;
  const unsigned short* B0 = Wt + (size_t)(nb + w * 64 + lr) * KX;

  // main K loop: k0 = 0..288 in steps of 32 (cols < 300 except spill into
  // next row, which is multiplied by Wt zero-pad -> harmless)
  #pragma unroll 1
  for (int k0 = 0; k0 < 288; k0 += BK) {
    bf16x8 av[4], bv[4];
    #pragma unroll
    for (int i = 0; i < 4; ++i) {
      size_t off = (size_t)(LEAF0 + rb + i * 16 + lr) * XSZ + k0 + ls * 8;
      f32x4 a0 = *(const f32x4*)(A0 + off);
      f32x4 a1 = *(const f32x4*)(A0 + off + 4);
      av[i] = pack8(a0, a1);
    }
    #pragma unroll
    for (int j = 0; j < 4; ++j)
      bv[j] = *(const bf16x8*)(B0 + (size_t)j * 16 * KX + k0 + ls * 8);
    #pragma unroll
    for (int i = 0; i < 4; ++i)
      #pragma unroll
      for (int j = 0; j < 4; ++j)
        acc[i][j] = __builtin_amdgcn_mfma_f32_16x16x32_bf16(av[i], bv[j], acc[i][j], 0, 0, 0);
  }
  { // tail k0 = 288: clamp addresses to stay inside x (values past col 299
    // are garbage but multiply Wt zero-pad)
    const int k0 = 288;
    bf16x8 av[4], bv[4];
    #pragma unroll
    for (int i = 0; i < 4; ++i) {
      size_t off = (size_t)(LEAF0 + rb + i * 16 + lr) * XSZ + k0 + ls * 8;
      size_t o0 = off     > xend ? xend : off;
      size_t o1 = off + 4 > xend ? xend : off + 4;
      f32x4 a0 = *(const f32x4*)(A0 + o0);
      f32x4 a1 = *(const f32x4*)(A0 + o1);
      av[i] = pack8(a0, a1);
    }
    #pragma unroll
    for (int j = 0; j < 4; ++j)
      bv[j] = *(const bf16x8*)(B0 + (size_t)j * 16 * KX + k0 + ls * 8);
    #pragma unroll
    for (int i = 0; i < 4; ++i)
      #pragma unroll
      for (int j = 0; j < 4; ++j)
        acc[i][j] = __builtin_amdgcn_mfma_f32_16x16x32_bf16(av[i], bv[j], acc[i][j], 0, 0, 0);
  }

  const int pc = nb + w * 64;
  #pragma unroll
  for (int i = 0; i < 4; ++i) {
    #pragma unroll
    for (int tt = 0; tt < 2; ++tt) {
      int col = (pc >> 1) + tt * 16 + lr;
      #pragma unroll
      for (int rr = 0; rr < 4; ++rr) {
        int row = rb + i * 16 + ls * 4 + rr;
        float th = ftanh_(acc[i][2 * tt][rr]     + bW[col]);
        float tc = ftanh_(acc[i][2 * tt + 1][rr] + bW[256 + col]);
        size_t node = (size_t)LEAF0 + row;
        hout[node * HSZ + col] = th;
        hb[node * HSZ + col]   = f2bf(th);
        cb[node * HSZ + col]   = (f16)tc;
      }
    }
  }
}

// ---------------------------------------------------------------------------
// Level GEMM for d >= 13, barrier-free reg-GEMM. Block = 4 waves = 64 rows x
// 256 perm-cols; wave w: cols nb + w*64 (= one 16-col h block x 4 gates).
// grid = (m/64) x 4. A rows shared by the 4 waves land in L1.
// ---------------------------------------------------------------------------
__global__ __launch_bounds__(256) void k_big(
    float* __restrict__ hbuf, unsigned short* __restrict__ hb,
    f16* __restrict__ cb,
    const unsigned short* __restrict__ Ut, const float* __restrict__ bU,
    int a, int m)
{
  const int t = threadIdx.x;
  const int lane = t & 63, w = t >> 6;
  const int lr = lane & 15, ls = lane >> 4;
  const int rb = (blockIdx.x >> 2) * 64;
  const int nb = (blockIdx.x & 3) * 256;

  f32x4 acc[4][4];
  #pragma unroll
  for (int i = 0; i < 4; ++i)
    #pragma unroll
    for (int j = 0; j < 4; ++j)
      #pragma unroll
      for (int e = 0; e < 4; ++e) acc[i][j][e] = 0.f;

  const unsigned short* A0 = hb + (size_t)(2 * a + 1) * HSZ;   // slab, row stride 512
  const unsigned short* B0 = Ut + (size_t)(nb + w * 64 + lr) * KU;

  #pragma unroll 1
  for (int k0 = 0; k0 < KU; k0 += BK) {
    bf16x8 av[4], bv[4];
    #pragma unroll
    for (int i = 0; i < 4; ++i)
      av[i] = *(const bf16x8*)(A0 + (size_t)(rb + i * 16 + lr) * KU + k0 + ls * 8);
    #pragma unroll
    for (int j = 0; j < 4; ++j)
      bv[j] = *(const bf16x8*)(B0 + (size_t)j * 16 * KU + k0 + ls * 8);
    #pragma unroll
    for (int i = 0; i < 4; ++i)
      #pragma unroll
      for (int j = 0; j < 4; ++j)
        acc[i][j] = __builtin_amdgcn_mfma_f32_16x16x32_bf16(av[i], bv[j], acc[i][j], 0, 0, 0);
  }

  const int pc = nb + w * 64;                // wave's 64-col span; frag j == gate j
  const int col = (pc >> 2) + lr;
  const float bi = bU[col], bo = bU[256 + col], bu = bU[512 + col], bff = bU[768 + col];
  #pragma unroll
  for (int i = 0; i < 4; ++i) {
    #pragma unroll
    for (int rr = 0; rr < 4; ++rr) {
      int row = rb + i * 16 + ls * 4 + rr;   // m % 64 == 0 for d >= 13: no mask
      float iv = fsig  (acc[i][0][rr] + bi);
      float ov = fsig  (acc[i][1][rr] + bo);
      float uv = ftanh_(acc[i][2][rr] + bu);
      float fv = fsig  (acc[i][3][rr] + bff);
      size_t node = (size_t)a + row;
      float cl = (float)cb[(2 * node + 1) * HSZ + col];
      float cr = (float)cb[(2 * node + 2) * HSZ + col];
      float cn = iv * uv + fv * (cl + cr);
      float hn = ov * ftanh_(cn);
      hbuf[node * HSZ + col] = hn;
      hb[node * HSZ + col]   = f2bf(hn);
      cb[node * HSZ + col]   = (f16)cn;
    }
  }
}

// ---------------------------------------------------------------------------
// Small levels (d <= 12): one wave per 16x64 output tile, direct global reads.
// grid = max(1,m/64) * 16 blocks of 256.
// ---------------------------------------------------------------------------
__global__ __launch_bounds__(256) void k_small(
    float* __restrict__ hbuf, unsigned short* __restrict__ hb,
    f16* __restrict__ cb,
    const unsigned short* __restrict__ Ut, const float* __restrict__ bU,
    int a, int m)
{
  const int t = threadIdx.x;
  const int lane = t & 63, w = t >> 6;
  const int lr = lane & 15, ls = lane >> 4;
  const int rb = (blockIdx.x >> 4) * 64 + w * 16;
  const int nb = (blockIdx.x & 15) * 64;
  if (rb >= m) return;

  const unsigned short* Arow = hb + (size_t)(2 * a + 1) * HSZ + (size_t)(rb + lr) * KU;
  const unsigned short* B0 = Ut + (size_t)(nb + lr) * KU;

  f32x4 acc[4];
  #pragma unroll
  for (int g = 0; g < 4; ++g)
    #pragma unroll
    for (int e = 0; e < 4; ++e) acc[g][e] = 0.f;

  for (int k0 = 0; k0 < KU; k0 += BK) {
    bf16x8 av = *(const bf16x8*)(Arow + k0 + ls * 8);
    #pragma unroll
    for (int g = 0; g < 4; ++g) {
      bf16x8 bv = *(const bf16x8*)(B0 + (size_t)g * 16 * KU + k0 + ls * 8);
      acc[g] = __builtin_amdgcn_mfma_f32_16x16x32_bf16(av, bv, acc[g], 0, 0, 0);
    }
  }

  const int col = (nb >> 2) + lr;
  const float bi = bU[col], bo = bU[256 + col], bu = bU[512 + col], bff = bU[768 + col];
  #pragma unroll
  for (int rr = 0; rr < 4; ++rr) {
    int row = rb + ls * 4 + rr;
    if (row < m) {
      float iv = fsig  (acc[0][rr] + bi);
      float ov = fsig  (acc[1][rr] + bo);
      float uv = ftanh_(acc[2][rr] + bu);
      float fv = fsig  (acc[3][rr] + bff);
      size_t node = (size_t)a + row;
      float cl = (float)cb[(2 * node + 1) * HSZ + col];
      float cr = (float)cb[(2 * node + 2) * HSZ + col];
      float cn = iv * uv + fv * (cl + cr);
      float hn = ov * ftanh_(cn);
      hbuf[node * HSZ + col] = hn;
      hb[node * HSZ + col]   = f2bf(hn);
      cb[node * HSZ + col]   = (f16)cn;
    }
  }
}

// ---------------------------------------------------------------------------
extern "C" void kernel_launch(void* const* d_in, const int* in_sizes, int n_in,
                              void* d_out, int out_size, void* d_ws, size_t ws_size,
                              hipStream_t stream) {
  const float* x  = (const float*)d_in[0];
  const float* W  = (const float*)d_in[1];
  const float* bW = (const float*)d_in[2];
  const float* U  = (const float*)d_in[3];
  const float* bU = (const float*)d_in[4];
  // d_in[5] = children (int32) — structurally 2i+1/2i+2 (complete binary tree).
  float* hout = (float*)d_out;
  char*  ws   = (char*)d_ws;

  // ws layout (269,810,688 B total):
  unsigned short* Ut = (unsigned short*)ws;                         // 1,048,576
  unsigned short* Wt = (unsigned short*)(ws + 1048576);             //   327,680
  f16*            cb = (f16*)(ws + 1048576 + 327680);               // 134,217,216
  unsigned short* hb = (unsigned short*)(ws + 1048576 + 327680
                                         + (size_t)N_NODES * HSZ * 2); // 134,217,216

  const int preptot = GATES * KU + WCOLS * KX;
  hipLaunchKernelGGL(k_prep, dim3((preptot + 255) / 256), dim3(256), 0, stream, W, U, Wt, Ut);

  hipLaunchKernelGGL(k_init, dim3((N_LEAF / 64) * 2), dim3(256), 0, stream,
                     x, Wt, bW, hout, hb, cb);

  for (int d = 16; d >= 0; --d) {
    int m = 1 << d, a = m - 1;
    if (d >= 13) {
      hipLaunchKernelGGL(k_big, dim3((m / 64) * 4), dim3(256), 0, stream,
                         hout, hb, cb, Ut, bU, a, m);
    } else {
      int gm = (m + 63) / 64; if (gm < 1) gm = 1;
      hipLaunchKernelGGL(k_small, dim3(gm * 16), dim3(256), 0, stream,
                         hout, hb, cb, Ut, bU, a, m);
    }
  }
}

// Round 8
// 642.251 us; speedup vs baseline: 1.5357x; 1.5357x over previous
//
#include <hip/hip_runtime.h>
#include <hip/hip_bf16.h>
#include <cstdint>
#include <cstddef>

#define N_NODES 262143
#define LEAF0   131071
#define N_LEAF  131072
#define HSZ     256
#define XSZ     300
#define KX      320        // XSZ padded to multiple of 32
#define KU      512
#define GATES   1024       // 4*H
#define WCOLS   512        // 2*H
#define BM      128
#define BK      32

typedef short bf16x8 __attribute__((ext_vector_type(8)));
typedef float f32x4 __attribute__((ext_vector_type(4)));
typedef _Float16 f16;

__device__ __forceinline__ unsigned short f2bf(float f) {
  union { float f; unsigned u; } v; v.f = f;
  unsigned r = v.u + 0x7FFFu + ((v.u >> 16) & 1u);   // RNE
  return (unsigned short)(r >> 16);
}
__device__ __forceinline__ unsigned cvt_pk(float lo, float hi) {
  unsigned r;
  asm("v_cvt_pk_bf16_f32 %0, %1, %2" : "=v"(r) : "v"(lo), "v"(hi));
  return r;
}
__device__ __forceinline__ bf16x8 pack8(f32x4 a0, f32x4 a1) {
  union { unsigned u[4]; bf16x8 v; } r;
  r.u[0] = cvt_pk(a0[0], a0[1]);
  r.u[1] = cvt_pk(a0[2], a0[3]);
  r.u[2] = cvt_pk(a1[0], a1[1]);
  r.u[3] = cvt_pk(a1[2], a1[3]);
  return r.v;
}
__device__ __forceinline__ void gld_lds16(const void* g, void* l) {
  __builtin_amdgcn_global_load_lds(
      (const __attribute__((address_space(1))) unsigned*)g,
      (__attribute__((address_space(3))) unsigned*)l, 16, 0, 0);
}
__device__ __forceinline__ float frcp(float x) { return __builtin_amdgcn_rcpf(x); }
__device__ __forceinline__ float fsig(float x) { return frcp(1.f + __expf(-x)); }
__device__ __forceinline__ float ftanh_(float x) { return 1.f - 2.f * frcp(1.f + __expf(2.f * x)); }

// ---------------------------------------------------------------------------
// Prep: cast + column-permute + transpose W and U into ws (bf16).
// U perm col p = 64*b + 16*g + j  <-  orig col 256*g + 16*b + j
// W perm col p = 32*b + 16*s + j  <-  orig col 256*s + 16*b + j
// ---------------------------------------------------------------------------
__global__ void k_prep(const float* __restrict__ W, const float* __restrict__ U,
                       unsigned short* __restrict__ Wt, unsigned short* __restrict__ Ut) {
  int tid = blockIdx.x * blockDim.x + threadIdx.x;
  const int totalU = GATES * KU;
  if (tid < totalU) {
    int p = tid >> 9;
    int k = tid & 511;
    int g = (p >> 4) & 3, b = p >> 6, j = p & 15;
    int oc = g * 256 + b * 16 + j;
    Ut[tid] = f2bf(U[(size_t)k * GATES + oc]);
  } else {
    int t2 = tid - totalU;
    if (t2 < WCOLS * KX) {
      int p = t2 / KX;
      int k = t2 - p * KX;
      int s = (p >> 4) & 1, b = p >> 5, j = p & 15;
      int oc = s * 256 + b * 16 + j;
      Wt[t2] = (k < XSZ) ? f2bf(W[(size_t)k * WCOLS + oc]) : (unsigned short)0;
    }
  }
}

// ---------------------------------------------------------------------------
// Leaf init: t = tanh(x @ W + bW); h -> hout(f32)+hb(bf16), c -> cb(f16)
// 3-buffer pipeline, prefetch distance 2, counted vmcnt + raw s_barrier.
// ---------------------------------------------------------------------------
__global__ __launch_bounds__(256) void k_init(
    const float* __restrict__ x, const unsigned short* __restrict__ Wt,
    const float* __restrict__ bW, float* __restrict__ hout,
    unsigned short* __restrict__ hb, f16* __restrict__ cb)
{
  __shared__ __attribute__((aligned(16))) float          As[3][BM * BK];   // 3x16 KB
  __shared__ __attribute__((aligned(16))) unsigned short Bs[3][BM * BK];   // 3x 8 KB
  const int t = threadIdx.x;
  const int lane = t & 63, w = t >> 6;
  const int wm = w >> 1, wn = w & 1;
  const int lr = lane & 15, ls = lane >> 4;

  const int nwg = gridDim.x;
  const int wg = (blockIdx.x & 7) * (nwg >> 3) + (blockIdx.x >> 3);
  const int mblk = wg >> 2, nblk = wg & 3;
  const int tileM = mblk * BM, tileN = nblk * 128;

  f32x4 acc[4][4];
  #pragma unroll
  for (int i = 0; i < 4; ++i)
    #pragma unroll
    for (int j = 0; j < 4; ++j)
      #pragma unroll
      for (int e = 0; e < 4; ++e) acc[i][j][e] = 0.f;

  const int arow  = lane >> 3;                       // A: 8 rows / 1KB issue (f32)
  const int aglog = (lane & 7) ^ arow;               // src granule = g ^ (row&7)
  const int brow  = lane >> 2;                       // B: 16 rows / 1KB issue (bf16)
  const int bswz  = ((lane & 3) ^ ((lane >> 3) & 3)) * 8;

  auto stage = [&](int k0, int buf) {                // 6 gld_lds per thread
    #pragma unroll
    for (int s = 0; s < 4; ++s) {
      int e = w * 4 + s;
      int col = k0 + aglog * 4;
      if (col >= XSZ) col = 0;                 // pad lanes: finite garbage * B(0) = 0
      const float* g = x + (size_t)(LEAF0 + tileM + e * 8 + arow) * XSZ + col;
      gld_lds16(g, (char*)As[buf] + e * 1024);
    }
    #pragma unroll
    for (int s = 0; s < 2; ++s) {
      int e = w * 2 + s;
      const unsigned short* g = Wt + (size_t)(tileN + e * 16 + brow) * KX + k0 + bswz;
      gld_lds16(g, (char*)Bs[buf] + e * 1024);
    }
  };

  const int NT = KX / BK;                      // 10
  stage(0, 0);
  stage(BK, 1);
  for (int it = 0; it < NT; ++it) {
    if (it < NT - 1) asm volatile("s_waitcnt vmcnt(6)" ::: "memory");
    else             asm volatile("s_waitcnt vmcnt(0)" ::: "memory");
    __builtin_amdgcn_s_barrier();
    __builtin_amdgcn_sched_barrier(0);
    asm volatile("" ::: "memory");
    if (it + 2 < NT) stage((it + 2) * BK, (it + 2) % 3);
    const int cur = it % 3;
    bf16x8 af[4], bfv[4];
    #pragma unroll
    for (int i = 0; i < 4; ++i) {
      int row = wm * 64 + i * 16 + lr;
      int gx = (2 * ls) ^ (lr & 7);
      f32x4 a0 = *(const f32x4*)((const char*)As[cur] + row * 128 + (gx << 4));
      f32x4 a1 = *(const f32x4*)((const char*)As[cur] + row * 128 + ((gx ^ 1) << 4));
      af[i] = pack8(a0, a1);
    }
    #pragma unroll
    for (int j = 0; j < 4; ++j) {
      int row = wn * 64 + j * 16 + lr;
      bfv[j] = *(const bf16x8*)((const char*)Bs[cur] + row * 64 + ((ls ^ ((lr >> 1) & 3)) << 4));
    }
    #pragma unroll
    for (int i = 0; i < 4; ++i)
      #pragma unroll
      for (int j = 0; j < 4; ++j)
        acc[i][j] = __builtin_amdgcn_mfma_f32_16x16x32_bf16(af[i], bfv[j], acc[i][j], 0, 0, 0);
  }

  const int pc = tileN + wn * 64;
  #pragma unroll
  for (int i = 0; i < 4; ++i) {
    #pragma unroll
    for (int tt = 0; tt < 2; ++tt) {
      int col = (pc >> 1) + tt * 16 + lr;
      #pragma unroll
      for (int rr = 0; rr < 4; ++rr) {
        int row = tileM + wm * 64 + i * 16 + ls * 4 + rr;
        float th = ftanh_(acc[i][2 * tt][rr]     + bW[col]);
        float tc = ftanh_(acc[i][2 * tt + 1][rr] + bW[256 + col]);
        size_t node = (size_t)LEAF0 + row;
        hout[node * HSZ + col] = th;
        hb[node * HSZ + col]   = f2bf(th);
        cb[node * HSZ + col]   = (f16)tc;
      }
    }
  }
}

// ---------------------------------------------------------------------------
// One tree level (d >= 12), fused, all-bf16 staging, 3-buffer counted-vmcnt
// pipeline (prefetch distance 2).
// ---------------------------------------------------------------------------
__global__ __launch_bounds__(256) void k_level(
    float* __restrict__ hbuf, unsigned short* __restrict__ hb,
    f16* __restrict__ cb,
    const unsigned short* __restrict__ Ut, const float* __restrict__ bU,
    int a, int m)
{
  __shared__ __attribute__((aligned(16))) unsigned short As[3][BM * BK];   // 3x8 KB
  __shared__ __attribute__((aligned(16))) unsigned short Bs[3][BM * BK];   // 3x8 KB
  const int t = threadIdx.x;
  const int lane = t & 63, w = t >> 6;
  const int wm = w >> 1, wn = w & 1;
  const int lr = lane & 15, ls = lane >> 4;

  const int nwg = gridDim.x;
  const int wg = (blockIdx.x & 7) * (nwg >> 3) + (blockIdx.x >> 3);
  const int mblk = wg >> 3, nblk = wg & 7;
  const int tileM = mblk * BM, tileN = nblk * 128;

  f32x4 acc[4][4];
  #pragma unroll
  for (int i = 0; i < 4; ++i)
    #pragma unroll
    for (int j = 0; j < 4; ++j)
      #pragma unroll
      for (int e = 0; e < 4; ++e) acc[i][j][e] = 0.f;

  const unsigned short* Abase = hb + (size_t)(2 * a + 1) * HSZ + (size_t)tileM * KU;
  const unsigned short* Bbase = Ut + (size_t)tileN * KU;

  const int brow = lane >> 2;
  const int bswz = ((lane & 3) ^ ((lane >> 3) & 3)) * 8;

  auto stage = [&](int k0, int buf) {                // 4 gld_lds per thread
    #pragma unroll
    for (int s = 0; s < 2; ++s) {
      int e = w * 2 + s;
      const unsigned short* g = Abase + (size_t)(e * 16 + brow) * KU + k0 + bswz;
      gld_lds16(g, (char*)As[buf] + e * 1024);
    }
    #pragma unroll
    for (int s = 0; s < 2; ++s) {
      int e = w * 2 + s;
      const unsigned short* g = Bbase + (size_t)(e * 16 + brow) * KU + k0 + bswz;
      gld_lds16(g, (char*)Bs[buf] + e * 1024);
    }
  };

  const int NT = KU / BK;                      // 16
  stage(0, 0);
  stage(BK, 1);
  for (int it = 0; it < NT; ++it) {
    if (it < NT - 1) asm volatile("s_waitcnt vmcnt(4)" ::: "memory");
    else             asm volatile("s_waitcnt vmcnt(0)" ::: "memory");
    __builtin_amdgcn_s_barrier();
    __builtin_amdgcn_sched_barrier(0);
    asm volatile("" ::: "memory");
    if (it + 2 < NT) stage((it + 2) * BK, (it + 2) % 3);
    const int cur = it % 3;
    bf16x8 af[4], bfv[4];
    #pragma unroll
    for (int i = 0; i < 4; ++i) {
      int row = wm * 64 + i * 16 + lr;
      af[i] = *(const bf16x8*)((const char*)As[cur] + row * 64 + ((ls ^ ((lr >> 1) & 3)) << 4));
    }
    #pragma unroll
    for (int j = 0; j < 4; ++j) {
      int row = wn * 64 + j * 16 + lr;
      bfv[j] = *(const bf16x8*)((const char*)Bs[cur] + row * 64 + ((ls ^ ((lr >> 1) & 3)) << 4));
    }
    #pragma unroll
    for (int i = 0; i < 4; ++i)
      #pragma unroll
      for (int j = 0; j < 4; ++j)
        acc[i][j] = __builtin_amdgcn_mfma_f32_16x16x32_bf16(af[i], bfv[j], acc[i][j], 0, 0, 0);
  }

  const int pc = tileN + wn * 64;            // frag j == gate g
  const int col = (pc >> 2) + lr;
  const float bi = bU[col], bo = bU[256 + col], bu = bU[512 + col], bff = bU[768 + col];
  #pragma unroll
  for (int i = 0; i < 4; ++i) {
    #pragma unroll
    for (int rr = 0; rr < 4; ++rr) {
      int noderow = tileM + wm * 64 + i * 16 + ls * 4 + rr;
      if (noderow < m) {
        float iv = fsig  (acc[i][0][rr] + bi);
        float ov = fsig  (acc[i][1][rr] + bo);
        float uv = ftanh_(acc[i][2][rr] + bu);
        float fv = fsig  (acc[i][3][rr] + bff);
        size_t node = (size_t)a + noderow;
        float cl = (float)cb[(2 * node + 1) * HSZ + col];
        float cr = (float)cb[(2 * node + 2) * HSZ + col];
        float cn = iv * uv + fv * (cl + cr);
        float hn = ov * ftanh_(cn);
        hbuf[node * HSZ + col] = hn;
        hb[node * HSZ + col]   = f2bf(hn);
        cb[node * HSZ + col]   = (f16)cn;
      }
    }
  }
}

// ---------------------------------------------------------------------------
// Small levels (d <= 11): one wave per 16x64 output tile, direct global reads
// (A slab and Ut are L2-resident at these sizes). grid = max(1,m/64)*16.
// ---------------------------------------------------------------------------
__global__ __launch_bounds__(256) void k_small(
    float* __restrict__ hbuf, unsigned short* __restrict__ hb,
    f16* __restrict__ cb,
    const unsigned short* __restrict__ Ut, const float* __restrict__ bU,
    int a, int m)
{
  const int t = threadIdx.x;
  const int lane = t & 63, w = t >> 6;
  const int lr = lane & 15, ls = lane >> 4;
  const int rb = (blockIdx.x >> 4) * 64 + w * 16;
  const int nb = (blockIdx.x & 15) * 64;
  if (rb >= m) return;

  const unsigned short* Arow = hb + (size_t)(2 * a + 1) * HSZ + (size_t)(rb + lr) * KU;
  const unsigned short* B0 = Ut + (size_t)(nb + lr) * KU;

  f32x4 acc[4];
  #pragma unroll
  for (int g = 0; g < 4; ++g)
    #pragma unroll
    for (int e = 0; e < 4; ++e) acc[g][e] = 0.f;

  for (int k0 = 0; k0 < KU; k0 += BK) {
    bf16x8 av = *(const bf16x8*)(Arow + k0 + ls * 8);
    #pragma unroll
    for (int g = 0; g < 4; ++g) {
      bf16x8 bv = *(const bf16x8*)(B0 + (size_t)g * 16 * KU + k0 + ls * 8);
      acc[g] = __builtin_amdgcn_mfma_f32_16x16x32_bf16(av, bv, acc[g], 0, 0, 0);
    }
  }

  const int col = (nb >> 2) + lr;
  const float bi = bU[col], bo = bU[256 + col], bu = bU[512 + col], bff = bU[768 + col];
  #pragma unroll
  for (int rr = 0; rr < 4; ++rr) {
    int row = rb + ls * 4 + rr;
    if (row < m) {
      float iv = fsig  (acc[0][rr] + bi);
      float ov = fsig  (acc[1][rr] + bo);
      float uv = ftanh_(acc[2][rr] + bu);
      float fv = fsig  (acc[3][rr] + bff);
      size_t node = (size_t)a + row;
      float cl = (float)cb[(2 * node + 1) * HSZ + col];
      float cr = (float)cb[(2 * node + 2) * HSZ + col];
      float cn = iv * uv + fv * (cl + cr);
      float hn = ov * ftanh_(cn);
      hbuf[node * HSZ + col] = hn;
      hb[node * HSZ + col]   = f2bf(hn);
      cb[node * HSZ + col]   = (f16)cn;
    }
  }
}

// ---------------------------------------------------------------------------
extern "C" void kernel_launch(void* const* d_in, const int* in_sizes, int n_in,
                              void* d_out, int out_size, void* d_ws, size_t ws_size,
                              hipStream_t stream) {
  const float* x  = (const float*)d_in[0];
  const float* W  = (const float*)d_in[1];
  const float* bW = (const float*)d_in[2];
  const float* U  = (const float*)d_in[3];
  const float* bU = (const float*)d_in[4];
  // d_in[5] = children (int32) — structurally 2i+1/2i+2 (complete binary tree).
  float* hout = (float*)d_out;
  char*  ws   = (char*)d_ws;

  // ws layout (269,810,688 B total):
  unsigned short* Ut = (unsigned short*)ws;                         // 1,048,576
  unsigned short* Wt = (unsigned short*)(ws + 1048576);             //   327,680
  f16*            cb = (f16*)(ws + 1048576 + 327680);               // 134,217,216
  unsigned short* hb = (unsigned short*)(ws + 1048576 + 327680
                                         + (size_t)N_NODES * HSZ * 2); // 134,217,216

  const int preptot = GATES * KU + WCOLS * KX;
  hipLaunchKernelGGL(k_prep, dim3((preptot + 255) / 256), dim3(256), 0, stream, W, U, Wt, Ut);

  hipLaunchKernelGGL(k_init, dim3((N_LEAF / BM) * 4), dim3(256), 0, stream,
                     x, Wt, bW, hout, hb, cb);

  for (int d = 16; d >= 0; --d) {
    int m = 1 << d, a = m - 1;
    if (d >= 12) {
      hipLaunchKernelGGL(k_level, dim3((m / BM) * 8), dim3(256), 0, stream,
                         hout, hb, cb, Ut, bU, a, m);
    } else {
      int gm = (m + 63) / 64; if (gm < 1) gm = 1;
      hipLaunchKernelGGL(k_small, dim3(gm * 16), dim3(256), 0, stream,
                         hout, hb, cb, Ut, bU, a, m);
    }
  }
}

// Round 9
// 606.959 us; speedup vs baseline: 1.6250x; 1.0581x over previous
//
#include <hip/hip_runtime.h>
#include <hip/hip_bf16.h>
#include <cstdint>
#include <cstddef>

#define N_NODES 262143
#define LEAF0   131071
#define N_LEAF  131072
#define HSZ     256
#define XSZ     300
#define KX      320        // XSZ padded to multiple of 32
#define KU      512
#define GATES   1024       // 4*H
#define WCOLS   512        // 2*H
#define BM      128
#define BK      32

typedef short bf16x8 __attribute__((ext_vector_type(8)));
typedef float f32x4 __attribute__((ext_vector_type(4)));
typedef _Float16 f16;

__device__ __forceinline__ unsigned short f2bf(float f) {
  union { float f; unsigned u; } v; v.f = f;
  unsigned r = v.u + 0x7FFFu + ((v.u >> 16) & 1u);   // RNE
  return (unsigned short)(r >> 16);
}
__device__ __forceinline__ unsigned cvt_pk(float lo, float hi) {
  unsigned r;
  asm("v_cvt_pk_bf16_f32 %0, %1, %2" : "=v"(r) : "v"(lo), "v"(hi));
  return r;
}
__device__ __forceinline__ bf16x8 pack8(f32x4 a0, f32x4 a1) {
  union { unsigned u[4]; bf16x8 v; } r;
  r.u[0] = cvt_pk(a0[0], a0[1]);
  r.u[1] = cvt_pk(a0[2], a0[3]);
  r.u[2] = cvt_pk(a1[0], a1[1]);
  r.u[3] = cvt_pk(a1[2], a1[3]);
  return r.v;
}
__device__ __forceinline__ void gld_lds16(const void* g, void* l) {
  __builtin_amdgcn_global_load_lds(
      (const __attribute__((address_space(1))) unsigned*)g,
      (__attribute__((address_space(3))) unsigned*)l, 16, 0, 0);
}
__device__ __forceinline__ float frcp(float x) { return __builtin_amdgcn_rcpf(x); }
__device__ __forceinline__ float fsig(float x) { return frcp(1.f + __expf(-x)); }
__device__ __forceinline__ float ftanh_(float x) { return 1.f - 2.f * frcp(1.f + __expf(2.f * x)); }

// ---------------------------------------------------------------------------
// Prep: cast + column-permute + transpose W and U into ws (bf16).
// U perm col p = 64*b + 16*g + j  <-  orig col 256*g + 16*b + j
// W perm col p = 32*b + 16*s + j  <-  orig col 256*s + 16*b + j
// ---------------------------------------------------------------------------
__global__ void k_prep(const float* __restrict__ W, const float* __restrict__ U,
                       unsigned short* __restrict__ Wt, unsigned short* __restrict__ Ut) {
  int tid = blockIdx.x * blockDim.x + threadIdx.x;
  const int totalU = GATES * KU;
  if (tid < totalU) {
    int p = tid >> 9;
    int k = tid & 511;
    int g = (p >> 4) & 3, b = p >> 6, j = p & 15;
    int oc = g * 256 + b * 16 + j;
    Ut[tid] = f2bf(U[(size_t)k * GATES + oc]);
  } else {
    int t2 = tid - totalU;
    if (t2 < WCOLS * KX) {
      int p = t2 / KX;
      int k = t2 - p * KX;
      int s = (p >> 4) & 1, b = p >> 5, j = p & 15;
      int oc = s * 256 + b * 16 + j;
      Wt[t2] = (k < XSZ) ? f2bf(W[(size_t)k * WCOLS + oc]) : (unsigned short)0;
    }
  }
}

// ---------------------------------------------------------------------------
// x (f32, leaf rows) -> xb (bf16, zero-padded to KX cols). Same RNE as the
// in-loop cvt_pk, so MFMA inputs are bit-identical.
// ---------------------------------------------------------------------------
__global__ __launch_bounds__(256) void k_xb(const float* __restrict__ x,
                                            unsigned short* __restrict__ xb) {
  int tid = blockIdx.x * blockDim.x + threadIdx.x;   // N_LEAF * 40 threads
  int r = tid / 40;
  int c0 = (tid - r * 40) * 8;
  const float* src = x + (size_t)(LEAF0 + r) * XSZ + c0;
  if (c0 + 8 <= XSZ) {
    f32x4 a0 = *(const f32x4*)src;
    f32x4 a1 = *(const f32x4*)(src + 4);
    *(bf16x8*)(xb + (size_t)r * KX + c0) = pack8(a0, a1);
  } else {
    union { unsigned short s[8]; bf16x8 v; } o;
    #pragma unroll
    for (int e = 0; e < 8; ++e) {
      int c = c0 + e;
      o.s[e] = (c < XSZ) ? f2bf(src[e]) : (unsigned short)0;
    }
    *(bf16x8*)(xb + (size_t)r * KX + c0) = o.v;
  }
}

// ---------------------------------------------------------------------------
// Leaf init (xb path): all-bf16 staging, 2-phase dbuf. Structure == k_level.
// ---------------------------------------------------------------------------
__global__ __launch_bounds__(256) void k_init_xb(
    const unsigned short* __restrict__ xb, const unsigned short* __restrict__ Wt,
    const float* __restrict__ bW, float* __restrict__ hout,
    unsigned short* __restrict__ hb, f16* __restrict__ cb)
{
  __shared__ __attribute__((aligned(16))) unsigned short As[2][BM * BK];   // 2x8 KB
  __shared__ __attribute__((aligned(16))) unsigned short Bs[2][BM * BK];   // 2x8 KB
  const int t = threadIdx.x;
  const int lane = t & 63, w = t >> 6;
  const int wm = w >> 1, wn = w & 1;
  const int lr = lane & 15, ls = lane >> 4;

  const int nwg = gridDim.x;
  const int wg = (blockIdx.x & 7) * (nwg >> 3) + (blockIdx.x >> 3);
  const int mblk = wg >> 2, nblk = wg & 3;
  const int tileM = mblk * BM, tileN = nblk * 128;

  f32x4 acc[4][4];
  #pragma unroll
  for (int i = 0; i < 4; ++i)
    #pragma unroll
    for (int j = 0; j < 4; ++j)
      #pragma unroll
      for (int e = 0; e < 4; ++e) acc[i][j][e] = 0.f;

  const unsigned short* Abase = xb + (size_t)tileM * KX;
  const unsigned short* Bbase = Wt + (size_t)tileN * KX;

  const int brow = lane >> 2;
  const int bswz = ((lane & 3) ^ ((lane >> 3) & 3)) * 8;

  auto stage = [&](int k0, int buf) {
    #pragma unroll
    for (int s = 0; s < 2; ++s) {
      int e = w * 2 + s;
      const unsigned short* g = Abase + (size_t)(e * 16 + brow) * KX + k0 + bswz;
      gld_lds16(g, (char*)As[buf] + e * 1024);
    }
    #pragma unroll
    for (int s = 0; s < 2; ++s) {
      int e = w * 2 + s;
      const unsigned short* g = Bbase + (size_t)(e * 16 + brow) * KX + k0 + bswz;
      gld_lds16(g, (char*)Bs[buf] + e * 1024);
    }
  };

  const int NT = KX / BK;                      // 10
  stage(0, 0);
  for (int it = 0; it < NT; ++it) {
    __syncthreads();
    if (it + 1 < NT) stage((it + 1) * BK, (it + 1) & 1);
    const int cur = it & 1;
    bf16x8 af[4], bfv[4];
    #pragma unroll
    for (int i = 0; i < 4; ++i) {
      int row = wm * 64 + i * 16 + lr;
      af[i] = *(const bf16x8*)((const char*)As[cur] + row * 64 + ((ls ^ ((lr >> 1) & 3)) << 4));
    }
    #pragma unroll
    for (int j = 0; j < 4; ++j) {
      int row = wn * 64 + j * 16 + lr;
      bfv[j] = *(const bf16x8*)((const char*)Bs[cur] + row * 64 + ((ls ^ ((lr >> 1) & 3)) << 4));
    }
    #pragma unroll
    for (int i = 0; i < 4; ++i)
      #pragma unroll
      for (int j = 0; j < 4; ++j)
        acc[i][j] = __builtin_amdgcn_mfma_f32_16x16x32_bf16(af[i], bfv[j], acc[i][j], 0, 0, 0);
  }

  const int pc = tileN + wn * 64;
  #pragma unroll
  for (int i = 0; i < 4; ++i) {
    #pragma unroll
    for (int tt = 0; tt < 2; ++tt) {
      int col = (pc >> 1) + tt * 16 + lr;
      #pragma unroll
      for (int rr = 0; rr < 4; ++rr) {
        int row = tileM + wm * 64 + i * 16 + ls * 4 + rr;
        float th = ftanh_(acc[i][2 * tt][rr]     + bW[col]);
        float tc = ftanh_(acc[i][2 * tt + 1][rr] + bW[256 + col]);
        size_t node = (size_t)LEAF0 + row;
        hout[node * HSZ + col] = th;
        hb[node * HSZ + col]   = f2bf(th);
        cb[node * HSZ + col]   = (f16)tc;
      }
    }
  }
}

// ---------------------------------------------------------------------------
// Leaf init (f32 fallback, R6-proven): f32 A staging with in-loop cvt.
// ---------------------------------------------------------------------------
__global__ __launch_bounds__(256) void k_init_f32(
    const float* __restrict__ x, const unsigned short* __restrict__ Wt,
    const float* __restrict__ bW, float* __restrict__ hout,
    unsigned short* __restrict__ hb, f16* __restrict__ cb)
{
  __shared__ __attribute__((aligned(16))) float          As[2][BM * BK];   // 2x16 KB
  __shared__ __attribute__((aligned(16))) unsigned short Bs[2][BM * BK];   // 2x 8 KB
  const int t = threadIdx.x;
  const int lane = t & 63, w = t >> 6;
  const int wm = w >> 1, wn = w & 1;
  const int lr = lane & 15, ls = lane >> 4;

  const int nwg = gridDim.x;
  const int wg = (blockIdx.x & 7) * (nwg >> 3) + (blockIdx.x >> 3);
  const int mblk = wg >> 2, nblk = wg & 3;
  const int tileM = mblk * BM, tileN = nblk * 128;

  f32x4 acc[4][4];
  #pragma unroll
  for (int i = 0; i < 4; ++i)
    #pragma unroll
    for (int j = 0; j < 4; ++j)
      #pragma unroll
      for (int e = 0; e < 4; ++e) acc[i][j][e] = 0.f;

  const int arow  = lane >> 3;
  const int aglog = (lane & 7) ^ arow;
  const int brow  = lane >> 2;
  const int bswz  = ((lane & 3) ^ ((lane >> 3) & 3)) * 8;

  auto stage = [&](int k0, int buf) {
    #pragma unroll
    for (int s = 0; s < 4; ++s) {
      int e = w * 4 + s;
      int col = k0 + aglog * 4;
      if (col >= XSZ) col = 0;
      const float* g = x + (size_t)(LEAF0 + tileM + e * 8 + arow) * XSZ + col;
      gld_lds16(g, (char*)As[buf] + e * 1024);
    }
    #pragma unroll
    for (int s = 0; s < 2; ++s) {
      int e = w * 2 + s;
      const unsigned short* g = Wt + (size_t)(tileN + e * 16 + brow) * KX + k0 + bswz;
      gld_lds16(g, (char*)Bs[buf] + e * 1024);
    }
  };

  const int NT = KX / BK;
  stage(0, 0);
  for (int it = 0; it < NT; ++it) {
    __syncthreads();
    if (it + 1 < NT) stage((it + 1) * BK, (it + 1) & 1);
    const int cur = it & 1;
    bf16x8 af[4], bfv[4];
    #pragma unroll
    for (int i = 0; i < 4; ++i) {
      int row = wm * 64 + i * 16 + lr;
      int gx = (2 * ls) ^ (lr & 7);
      f32x4 a0 = *(const f32x4*)((const char*)As[cur] + row * 128 + (gx << 4));
      f32x4 a1 = *(const f32x4*)((const char*)As[cur] + row * 128 + ((gx ^ 1) << 4));
      af[i] = pack8(a0, a1);
    }
    #pragma unroll
    for (int j = 0; j < 4; ++j) {
      int row = wn * 64 + j * 16 + lr;
      bfv[j] = *(const bf16x8*)((const char*)Bs[cur] + row * 64 + ((ls ^ ((lr >> 1) & 3)) << 4));
    }
    #pragma unroll
    for (int i = 0; i < 4; ++i)
      #pragma unroll
      for (int j = 0; j < 4; ++j)
        acc[i][j] = __builtin_amdgcn_mfma_f32_16x16x32_bf16(af[i], bfv[j], acc[i][j], 0, 0, 0);
  }

  const int pc = tileN + wn * 64;
  #pragma unroll
  for (int i = 0; i < 4; ++i) {
    #pragma unroll
    for (int tt = 0; tt < 2; ++tt) {
      int col = (pc >> 1) + tt * 16 + lr;
      #pragma unroll
      for (int rr = 0; rr < 4; ++rr) {
        int row = tileM + wm * 64 + i * 16 + ls * 4 + rr;
        float th = ftanh_(acc[i][2 * tt][rr]     + bW[col]);
        float tc = ftanh_(acc[i][2 * tt + 1][rr] + bW[256 + col]);
        size_t node = (size_t)LEAF0 + row;
        hout[node * HSZ + col] = th;
        hb[node * HSZ + col]   = f2bf(th);
        cb[node * HSZ + col]   = (f16)tc;
      }
    }
  }
}

// ---------------------------------------------------------------------------
// One tree level (d >= 12), fused, all-bf16 staging, 2-phase dbuf (R6).
// ---------------------------------------------------------------------------
__global__ __launch_bounds__(256) void k_level(
    float* __restrict__ hbuf, unsigned short* __restrict__ hb,
    f16* __restrict__ cb,
    const unsigned short* __restrict__ Ut, const float* __restrict__ bU,
    int a, int m)
{
  __shared__ __attribute__((aligned(16))) unsigned short As[2][BM * BK];   // 2x8 KB
  __shared__ __attribute__((aligned(16))) unsigned short Bs[2][BM * BK];   // 2x8 KB
  const int t = threadIdx.x;
  const int lane = t & 63, w = t >> 6;
  const int wm = w >> 1, wn = w & 1;
  const int lr = lane & 15, ls = lane >> 4;

  const int nwg = gridDim.x;
  const int wg = (blockIdx.x & 7) * (nwg >> 3) + (blockIdx.x >> 3);
  const int mblk = wg >> 3, nblk = wg & 7;
  const int tileM = mblk * BM, tileN = nblk * 128;

  f32x4 acc[4][4];
  #pragma unroll
  for (int i = 0; i < 4; ++i)
    #pragma unroll
    for (int j = 0; j < 4; ++j)
      #pragma unroll
      for (int e = 0; e < 4; ++e) acc[i][j][e] = 0.f;

  const unsigned short* Abase = hb + (size_t)(2 * a + 1) * HSZ + (size_t)tileM * KU;
  const unsigned short* Bbase = Ut + (size_t)tileN * KU;

  const int brow = lane >> 2;
  const int bswz = ((lane & 3) ^ ((lane >> 3) & 3)) * 8;

  auto stage = [&](int k0, int buf) {
    #pragma unroll
    for (int s = 0; s < 2; ++s) {
      int e = w * 2 + s;
      const unsigned short* g = Abase + (size_t)(e * 16 + brow) * KU + k0 + bswz;
      gld_lds16(g, (char*)As[buf] + e * 1024);
    }
    #pragma unroll
    for (int s = 0; s < 2; ++s) {
      int e = w * 2 + s;
      const unsigned short* g = Bbase + (size_t)(e * 16 + brow) * KU + k0 + bswz;
      gld_lds16(g, (char*)Bs[buf] + e * 1024);
    }
  };

  const int NT = KU / BK;                      // 16
  stage(0, 0);
  for (int it = 0; it < NT; ++it) {
    __syncthreads();
    if (it + 1 < NT) stage((it + 1) * BK, (it + 1) & 1);
    const int cur = it & 1;
    bf16x8 af[4], bfv[4];
    #pragma unroll
    for (int i = 0; i < 4; ++i) {
      int row = wm * 64 + i * 16 + lr;
      af[i] = *(const bf16x8*)((const char*)As[cur] + row * 64 + ((ls ^ ((lr >> 1) & 3)) << 4));
    }
    #pragma unroll
    for (int j = 0; j < 4; ++j) {
      int row = wn * 64 + j * 16 + lr;
      bfv[j] = *(const bf16x8*)((const char*)Bs[cur] + row * 64 + ((ls ^ ((lr >> 1) & 3)) << 4));
    }
    #pragma unroll
    for (int i = 0; i < 4; ++i)
      #pragma unroll
      for (int j = 0; j < 4; ++j)
        acc[i][j] = __builtin_amdgcn_mfma_f32_16x16x32_bf16(af[i], bfv[j], acc[i][j], 0, 0, 0);
  }

  const int pc = tileN + wn * 64;            // frag j == gate g
  const int col = (pc >> 2) + lr;
  const float bi = bU[col], bo = bU[256 + col], bu = bU[512 + col], bff = bU[768 + col];
  #pragma unroll
  for (int i = 0; i < 4; ++i) {
    #pragma unroll
    for (int rr = 0; rr < 4; ++rr) {
      int noderow = tileM + wm * 64 + i * 16 + ls * 4 + rr;
      if (noderow < m) {
        float iv = fsig  (acc[i][0][rr] + bi);
        float ov = fsig  (acc[i][1][rr] + bo);
        float uv = ftanh_(acc[i][2][rr] + bu);
        float fv = fsig  (acc[i][3][rr] + bff);
        size_t node = (size_t)a + noderow;
        float cl = (float)cb[(2 * node + 1) * HSZ + col];
        float cr = (float)cb[(2 * node + 2) * HSZ + col];
        float cn = iv * uv + fv * (cl + cr);
        float hn = ov * ftanh_(cn);
        hbuf[node * HSZ + col] = hn;
        hb[node * HSZ + col]   = f2bf(hn);
        cb[node * HSZ + col]   = (f16)cn;
      }
    }
  }
}

// ---------------------------------------------------------------------------
// Small levels (d <= 11): one wave per 16x64 output tile, direct global reads
// (A slab and Ut are L2-resident at these sizes). grid = max(1,m/64)*16.
// ---------------------------------------------------------------------------
__global__ __launch_bounds__(256) void k_small(
    float* __restrict__ hbuf, unsigned short* __restrict__ hb,
    f16* __restrict__ cb,
    const unsigned short* __restrict__ Ut, const float* __restrict__ bU,
    int a, int m)
{
  const int t = threadIdx.x;
  const int lane = t & 63, w = t >> 6;
  const int lr = lane & 15, ls = lane >> 4;
  const int rb = (blockIdx.x >> 4) * 64 + w * 16;
  const int nb = (blockIdx.x & 15) * 64;
  if (rb >= m) return;

  const unsigned short* Arow = hb + (size_t)(2 * a + 1) * HSZ + (size_t)(rb + lr) * KU;
  const unsigned short* B0 = Ut + (size_t)(nb + lr) * KU;

  f32x4 acc[4];
  #pragma unroll
  for (int g = 0; g < 4; ++g)
    #pragma unroll
    for (int e = 0; e < 4; ++e) acc[g][e] = 0.f;

  for (int k0 = 0; k0 < KU; k0 += BK) {
    bf16x8 av = *(const bf16x8*)(Arow + k0 + ls * 8);
    #pragma unroll
    for (int g = 0; g < 4; ++g) {
      bf16x8 bv = *(const bf16x8*)(B0 + (size_t)g * 16 * KU + k0 + ls * 8);
      acc[g] = __builtin_amdgcn_mfma_f32_16x16x32_bf16(av, bv, acc[g], 0, 0, 0);
    }
  }

  const int col = (nb >> 2) + lr;
  const float bi = bU[col], bo = bU[256 + col], bu = bU[512 + col], bff = bU[768 + col];
  #pragma unroll
  for (int rr = 0; rr < 4; ++rr) {
    int row = rb + ls * 4 + rr;
    if (row < m) {
      float iv = fsig  (acc[0][rr] + bi);
      float ov = fsig  (acc[1][rr] + bo);
      float uv = ftanh_(acc[2][rr] + bu);
      float fv = fsig  (acc[3][rr] + bff);
      size_t node = (size_t)a + row;
      float cl = (float)cb[(2 * node + 1) * HSZ + col];
      float cr = (float)cb[(2 * node + 2) * HSZ + col];
      float cn = iv * uv + fv * (cl + cr);
      float hn = ov * ftanh_(cn);
      hbuf[node * HSZ + col] = hn;
      hb[node * HSZ + col]   = f2bf(hn);
      cb[node * HSZ + col]   = (f16)cn;
    }
  }
}

// ---------------------------------------------------------------------------
extern "C" void kernel_launch(void* const* d_in, const int* in_sizes, int n_in,
                              void* d_out, int out_size, void* d_ws, size_t ws_size,
                              hipStream_t stream) {
  const float* x  = (const float*)d_in[0];
  const float* W  = (const float*)d_in[1];
  const float* bW = (const float*)d_in[2];
  const float* U  = (const float*)d_in[3];
  const float* bU = (const float*)d_in[4];
  // d_in[5] = children (int32) — structurally 2i+1/2i+2 (complete binary tree).
  float* hout = (float*)d_out;
  char*  ws   = (char*)d_ws;

  // ws layout:
  unsigned short* Ut = (unsigned short*)ws;                         // 1,048,576
  unsigned short* Wt = (unsigned short*)(ws + 1048576);             //   327,680
  f16*            cb = (f16*)(ws + 1048576 + 327680);               // 134,217,216
  unsigned short* hb = (unsigned short*)(ws + 1048576 + 327680
                                         + (size_t)N_NODES * HSZ * 2); // 134,217,216
  const size_t XBOFF = 1048576ull + 327680ull + 2ull * 134217216ull;   // 269,810,688
  const size_t XBSZ  = (size_t)N_LEAF * KX * 2;                        //  83,886,080
  unsigned short* xb = (unsigned short*)(ws + XBOFF);
  bool use_xb = (ws_size >= XBOFF + XBSZ);

  const int preptot = GATES * KU + WCOLS * KX;
  hipLaunchKernelGGL(k_prep, dim3((preptot + 255) / 256), dim3(256), 0, stream, W, U, Wt, Ut);

  if (use_xb) {
    hipLaunchKernelGGL(k_xb, dim3(N_LEAF * 40 / 256), dim3(256), 0, stream, x, xb);
    hipLaunchKernelGGL(k_init_xb, dim3((N_LEAF / BM) * 4), dim3(256), 0, stream,
                       xb, Wt, bW, hout, hb, cb);
  } else {
    hipLaunchKernelGGL(k_init_f32, dim3((N_LEAF / BM) * 4), dim3(256), 0, stream,
                       x, Wt, bW, hout, hb, cb);
  }

  for (int d = 16; d >= 0; --d) {
    int m = 1 << d, a = m - 1;
    if (d >= 12) {
      hipLaunchKernelGGL(k_level, dim3((m / BM) * 8), dim3(256), 0, stream,
                         hout, hb, cb, Ut, bU, a, m);
    } else {
      int gm = (m + 63) / 64; if (gm < 1) gm = 1;
      hipLaunchKernelGGL(k_small, dim3(gm * 16), dim3(256), 0, stream,
                         hout, hb, cb, Ut, bU, a, m);
    }
  }
}